// Round 1
// baseline (315.761 us; speedup 1.0000x reference)
//
#include <hip/hip_runtime.h>

// RandomTimeMask: out[n,c,l] = x[n,c,l] if ((l - starts[n,c]) mod L) >= L/4 else 0
// N=128, C=12, L=32768, mask_len=8192. Memory-bound elementwise.
//
// Layout facts exploited:
//  - L = 32768 = 8192 float4 per row; a 256-thread block covers 1024 floats,
//    and 32768 % 1024 == 0, so every block lies within ONE (n,c) row ->
//    starts[row] is wave-uniform (single scalar-cached load).
//  - L power of 2: circular offset = (l - s) & (L-1), valid for negative
//    two's-complement since l - s is in (-L, L).
//  - If all 4 lanes of a float4 are masked, skip the load entirely (mask is
//    an 8192-long contiguous circular run -> branch is wave-uniform except
//    at the two run boundaries). Saves ~25% of read traffic.

__global__ __launch_bounds__(256) void RandomTimeMask_kernel(
    const float4* __restrict__ x,
    const int* __restrict__ starts,
    float4* __restrict__ out,
    int total4)
{
    int idx4 = blockIdx.x * blockDim.x + threadIdx.x;
    if (idx4 >= total4) return;

    const int LM   = 32767;  // L - 1
    const int MLEN = 8192;   // mask length

    int row = idx4 >> 13;          // idx4 / (L/4)
    int l   = (idx4 & 8191) << 2;  // first element index within row

    int s    = starts[row];        // wave-uniform within a block
    int base = l - s;

    bool k0 = (( base      ) & LM) >= MLEN;
    bool k1 = ((base + 1) & LM) >= MLEN;
    bool k2 = ((base + 2) & LM) >= MLEN;
    bool k3 = ((base + 3) & LM) >= MLEN;

    float4 v;
    if (k0 | k1 | k2 | k3) {
        v = x[idx4];
        v.x = k0 ? v.x : 0.0f;
        v.y = k1 ? v.y : 0.0f;
        v.z = k2 ? v.z : 0.0f;
        v.w = k3 ? v.w : 0.0f;
    } else {
        v = make_float4(0.0f, 0.0f, 0.0f, 0.0f);
    }
    out[idx4] = v;
}

extern "C" void kernel_launch(void* const* d_in, const int* in_sizes, int n_in,
                              void* d_out, int out_size, void* d_ws, size_t ws_size,
                              hipStream_t stream) {
    const float4* x      = (const float4*)d_in[0];
    const int*    starts = (const int*)d_in[1];
    float4*       out    = (float4*)d_out;

    int total4 = out_size >> 2;                 // 12,582,912 float4
    int block  = 256;
    int grid   = (total4 + block - 1) / block;  // 49,152 blocks

    RandomTimeMask_kernel<<<grid, block, 0, stream>>>(x, starts, out, total4);
}

// Round 2
// 309.471 us; speedup vs baseline: 1.0203x; 1.0203x over previous
//
#include <hip/hip_runtime.h>

// RandomTimeMask: out[n,c,l] = x[n,c,l] if ((l - starts[n,c]) mod L) >= L/4 else 0
// N=128, C=12, L=32768, mask_len=8192. Memory-bound elementwise streaming.
//
// R2 changes vs R1:
//  - 2 float4 per thread (block covers 512 float4 = 2048 floats; 8192 float4
//    per row % 512 == 0, so a block still lies in ONE row -> starts uniform).
//  - Non-temporal loads/stores (pure streaming, zero reuse) via
//    __builtin_nontemporal_* on ext_vector float4 (HIP's struct float4 is not
//    accepted by the builtin).
//  - Masked-run skip kept: if all 4 elems masked, no global load (~25% fetch
//    saved; mask is one 8192-long circular run per row -> wave-uniform branch).

typedef float f4 __attribute__((ext_vector_type(4)));

__global__ __launch_bounds__(256) void RandomTimeMask_kernel(
    const f4* __restrict__ x,
    const int* __restrict__ starts,
    f4* __restrict__ out)
{
    const int LM   = 32767;  // L - 1
    const int MLEN = 8192;   // mask length

    int base4 = blockIdx.x * 512 + threadIdx.x;  // first float4 index
    int row   = base4 >> 13;                     // / 8192 float4-per-row
    int s     = starts[row];                     // block-uniform

#pragma unroll
    for (int j = 0; j < 2; ++j) {
        int idx4 = base4 + j * 256;
        int b    = ((idx4 & 8191) << 2) - s;     // elem offset minus start

        bool k0 = ((b    ) & LM) >= MLEN;
        bool k1 = ((b + 1) & LM) >= MLEN;
        bool k2 = ((b + 2) & LM) >= MLEN;
        bool k3 = ((b + 3) & LM) >= MLEN;

        f4 v = {0.0f, 0.0f, 0.0f, 0.0f};
        if (k0 | k1 | k2 | k3) {                 // wave-uniform except at run edges
            v = __builtin_nontemporal_load(&x[idx4]);
            v[0] = k0 ? v[0] : 0.0f;
            v[1] = k1 ? v[1] : 0.0f;
            v[2] = k2 ? v[2] : 0.0f;
            v[3] = k3 ? v[3] : 0.0f;
        }
        __builtin_nontemporal_store(v, &out[idx4]);
    }
}

extern "C" void kernel_launch(void* const* d_in, const int* in_sizes, int n_in,
                              void* d_out, int out_size, void* d_ws, size_t ws_size,
                              hipStream_t stream) {
    const f4*  x      = (const f4*)d_in[0];
    const int* starts = (const int*)d_in[1];
    f4*        out    = (f4*)d_out;

    int total4 = out_size >> 2;      // 12,582,912 float4
    int block  = 256;
    int grid   = total4 / 512;       // 24,576 blocks, 2 float4/thread

    RandomTimeMask_kernel<<<grid, block, 0, stream>>>(x, starts, out);
}